// Round 6
// baseline (2190.637 us; speedup 1.0000x reference)
//
#include <hip/hip_runtime.h>

#define B_ 4
#define L_ 4096
#define HID_ 1024
#define H_ 16
#define D_ 64
#define DM_ 128
#define CS_ 64
#define NCH_ 64
#define EPS_ 1e-6f

typedef __attribute__((ext_vector_type(8))) short bfrag_t;   // 8 bf16 = 4 VGPRs
typedef __attribute__((ext_vector_type(4))) float facc_t;    // MFMA C/D

#define MFMA16(a,b,c) __builtin_amdgcn_mfma_f32_16x16x32_bf16(a,b,c,0,0,0)

__device__ __forceinline__ float sigf(float x){ return 1.0f/(1.0f + __expf(-x)); }

__device__ __forceinline__ unsigned f2bfu(float x){   // fp32 -> bf16 RNE
  unsigned u = __float_as_uint(x);
  return (u + 0x7fffu + ((u>>16)&1u)) >> 16;
}
__device__ __forceinline__ float bf2f(unsigned short s){
  return __uint_as_float(((unsigned)s)<<16);
}

// wave64 sum via DPP row_shr prefix + readlane combine (no LDS pipe).
#define DPP_ADD_(x, ctrl) x += __int_as_float(__builtin_amdgcn_update_dpp(0, __float_as_int(x), ctrl, 0xf, 0xf, true))
__device__ __forceinline__ float wsum64(float x){
  DPP_ADD_(x, 0x111);
  DPP_ADD_(x, 0x112);
  DPP_ADD_(x, 0x114);
  DPP_ADD_(x, 0x118);
  const float a = __int_as_float(__builtin_amdgcn_readlane(__float_as_int(x), 15));
  const float b = __int_as_float(__builtin_amdgcn_readlane(__float_as_int(x), 31));
  const float c = __int_as_float(__builtin_amdgcn_readlane(__float_as_int(x), 47));
  const float d = __int_as_float(__builtin_amdgcn_readlane(__float_as_int(x), 63));
  return (a+b)+(c+d);
}

// ---------------------------------------------------------------------------
// cast fp32 -> bf16 for x and Wq/Wk/Wv
// ---------------------------------------------------------------------------
__global__ __launch_bounds__(256) void cast_kernel(
    const float* __restrict__ x,  const float* __restrict__ wq,
    const float* __restrict__ wk, const float* __restrict__ wv,
    unsigned short* __restrict__ xb,  unsigned short* __restrict__ wqb,
    unsigned short* __restrict__ wkb, unsigned short* __restrict__ wvb)
{
  const int bid = blockIdx.x;
  const float* s; unsigned short* d; int base;
  if (bid < 16384){ s = x; d = xb; base = bid*1024; }
  else {
    int r = bid - 16384; const int a = r >> 10; r &= 1023; base = r*1024;
    s = (a==0)?wq:(a==1)?wk:wv;
    d = (a==0)?wqb:(a==1)?wkb:wvb;
  }
  const int i = base + threadIdx.x*4;
  float4 v = *(const float4*)(s + i);
  unsigned lo = f2bfu(v.x) | (f2bfu(v.y)<<16);
  unsigned hi = f2bfu(v.z) | (f2bfu(v.w)<<16);
  uint2 o; o.x = lo; o.y = hi;
  *(uint2*)(d + i) = o;
}

// ---------------------------------------------------------------------------
// Fused QKV GEMM, head-major output: dst[((t*B+b)*H+h)*L + l]*64 + d
// ---------------------------------------------------------------------------
__global__ __launch_bounds__(256, 2) void gemm_bf16_nt(
    const unsigned short* __restrict__ A, const unsigned short* __restrict__ Bw,
    unsigned short* __restrict__ C, int M, int N, int K)
{
  __shared__ __align__(16) unsigned short As[128*32];
  __shared__ __align__(16) unsigned short Bs[128*32];
  const int tid = threadIdx.x;
  const int lane = tid & 63, wave = tid >> 6;
  const int lq = lane & 15, quad = lane >> 4;
  const int m0 = blockIdx.y*128, n0 = blockIdx.x*128;
  const int row = tid >> 2, ks = (tid & 3)*8;
  const int mo = (wave & 1)*64, no = (wave >> 1)*64;

  const unsigned short* pa0 = A  + (size_t)(m0 + row)*K + ks;
  const unsigned short* pa1 = pa0 + (size_t)64*K;
  const unsigned short* pb0 = Bw + (size_t)(n0 + row)*K + ks;
  const unsigned short* pb1 = pb0 + (size_t)64*K;

  uint4 ra0 = *(const uint4*)pa0;
  uint4 ra1 = *(const uint4*)pa1;
  uint4 rb0 = *(const uint4*)pb0;
  uint4 rb1 = *(const uint4*)pb1;

  facc_t acc[4][4];
  #pragma unroll
  for (int i=0;i<4;++i)
    #pragma unroll
    for (int j=0;j<4;++j) acc[i][j] = (facc_t){0.f,0.f,0.f,0.f};

  const int kiters = K >> 5;
  for (int kt = 0; kt < kiters; ++kt){
    *(uint4*)&As[row*32 + ks]      = ra0;
    *(uint4*)&As[(row+64)*32 + ks] = ra1;
    *(uint4*)&Bs[row*32 + ks]      = rb0;
    *(uint4*)&Bs[(row+64)*32 + ks] = rb1;
    __syncthreads();
    if (kt+1 < kiters){
      const int off = (kt+1)*32;
      ra0 = *(const uint4*)(pa0 + off);
      ra1 = *(const uint4*)(pa1 + off);
      rb0 = *(const uint4*)(pb0 + off);
      rb1 = *(const uint4*)(pb1 + off);
    }
    bfrag_t af[4], bf[4];
    #pragma unroll
    for (int mt=0;mt<4;++mt) af[mt] = *(const bfrag_t*)&As[(mo+mt*16+lq)*32 + quad*8];
    #pragma unroll
    for (int nt=0;nt<4;++nt) bf[nt] = *(const bfrag_t*)&Bs[(no+nt*16+lq)*32 + quad*8];
    #pragma unroll
    for (int mt=0;mt<4;++mt)
      #pragma unroll
      for (int nt=0;nt<4;++nt)
        acc[mt][nt] = MFMA16(af[mt], bf[nt], acc[mt][nt]);
    __syncthreads();
  }

  #pragma unroll
  for (int mt=0;mt<4;++mt)
    #pragma unroll
    for (int nt=0;nt<4;++nt)
      #pragma unroll
      for (int r=0;r<4;++r){
        const int rr = m0 + mo + mt*16 + quad*4 + r;
        const int cc = n0 + no + nt*16 + lq;
        const int t = cc >> 10, hh = (cc >> 6) & 15, dd = cc & 63;
        const int b = rr >> 12, l = rr & 4095;
        C[((((size_t)t*B_ + b)*H_ + hh)*L_ + l)*64 + dd]
            = (unsigned short)f2bfu(acc[mt][nt][r]);
      }
}

// ---------------------------------------------------------------------------
// Gate logits + per-chunk suffix products. Each block = one (b, chunk).
// ---------------------------------------------------------------------------
__global__ __launch_bounds__(256, 2) void gates_kernel(
  const float* __restrict__ x,
  const float* __restrict__ mdw, const float* __restrict__ mdb,
  const float* __restrict__ sw,  const float* __restrict__ sb,
  const float* __restrict__ lw,  const float* __restrict__ lb,
  float* __restrict__ cmb, float* __restrict__ c1b, float* __restrict__ ppb)
{
  __shared__ float xs[64][68];
  __shared__ float wg[48][68];
  const int tid = threadIdx.x;
  const int m0 = blockIdx.x * 64;
  const int tx = tid & 15, ty = tid >> 4;
  float acc[4][3];
  #pragma unroll
  for (int r=0;r<4;++r){ acc[r][0]=0.f; acc[r][1]=0.f; acc[r][2]=0.f; }

  for (int k0 = 0; k0 < HID_; k0 += 64){
    {
      const int r = tid >> 2, kq = tid & 3;
      const float* xp = x + (size_t)(m0 + r) * HID_ + k0 + kq*16;
      #pragma unroll
      for (int u=0;u<4;++u){
        float4 v = *(const float4*)(xp + u*4);
        *(float4*)&xs[r][kq*16 + u*4] = v;
      }
    }
    #pragma unroll
    for (int u=0;u<3;++u){
      const int idx = tid + 256*u;
      const int gi = idx >> 4, q = idx & 15;
      const float* wp = (gi < 16) ? (mdw + (size_t)gi*HID_)
                      : (gi < 32) ? (sw  + (size_t)(gi-16)*HID_)
                                  : (lw  + (size_t)(gi-32)*HID_);
      float4 v = *(const float4*)(wp + k0 + q*4);
      *(float4*)&wg[gi][q*4] = v;
    }
    __syncthreads();
    for (int kk=0; kk<64; ++kk){
      float xv[4], wv[3];
      #pragma unroll
      for (int r=0;r<4;++r) xv[r] = xs[ty*4+r][kk];
      #pragma unroll
      for (int gg=0;gg<3;++gg) wv[gg] = wg[tx*3+gg][kk];
      #pragma unroll
      for (int r=0;r<4;++r)
        #pragma unroll
        for (int gg=0;gg<3;++gg) acc[r][gg] += xv[r]*wv[gg];
    }
    __syncthreads();
  }

  float (*ls)[68] = xs;
  #pragma unroll
  for (int gg=0; gg<3; ++gg){
    const int gi = tx*3 + gg;
    const int s = gi >> 4, hh = gi & 15;
    const float bias = (s==0) ? mdb[hh] : (s==1) ? sb[hh] : lb[hh];
    #pragma unroll
    for (int r=0;r<4;++r) ls[gi][ty*4+r] = acc[r][gg] + bias;
  }
  __syncthreads();

  const int lane = tid & 63, wv2 = tid >> 6;
  const int b = m0 >> 12, n = (m0 & 4095) >> 6;
  #pragma unroll
  for (int u=0;u<4;++u){
    const int hh = wv2*4 + u;
    const float md = 1.0f - sigf(ls[hh][lane]);
    const float sd = sigf(ls[16+hh][lane]);
    const float lr = sigf(ls[32+hh][lane]);
    float vm = md, vs = sd;
    #pragma unroll
    for (int off = 1; off < 64; off <<= 1){
      float om = __shfl_down(vm, off);
      float os = __shfl_down(vs, off);
      if (lane + off < 64){ vm *= om; vs *= os; }
    }
    float mex = __shfl_down(vm, 1);
    float sex = __shfl_down(vs, 1);
    if (lane == 63){ mex = 1.0f; sex = 1.0f; }
    const size_t base = ((size_t)(b*16 + hh)*NCH_ + n)*64;
    cmb[base + lane] = mex;
    c1b[base + lane] = -lr * sex;
    if (lane == 0){
      ppb[((size_t)(b*16+hh)*NCH_ + n)*2 + 0] = vm;
      ppb[((size_t)(b*16+hh)*NCH_ + n)*2 + 1] = vs;
    }
  }
}

// ---------------------------------------------------------------------------
// Parallel q/k staging: conv + SiLU + RMSNorm, head-major bf16 in/out.
// Block = (bh, 64-row chunk); wave = 16 rows (lane = channel d).
// ---------------------------------------------------------------------------
__global__ __launch_bounds__(256, 2) void stage_kernel(
  const unsigned short* __restrict__ qg, const unsigned short* __restrict__ kg,
  unsigned short* __restrict__ sq, unsigned short* __restrict__ sk,
  const float* __restrict__ cqw, const float* __restrict__ cqb,
  const float* __restrict__ ckw, const float* __restrict__ ckb,
  const float* __restrict__ qnw, const float* __restrict__ knw)
{
  const int bh = blockIdx.x >> 6;
  const int l0 = (blockIdx.x & 63) * 64;
  const int tid = threadIdx.x;
  const int lane = tid & 63, wave = tid >> 6;
  const int c = (bh & 15)*64 + lane;
  float wq[4], wk[4];
  #pragma unroll
  for (int t=0;t<4;++t){ wq[t]=cqw[c*4+t]; wk[t]=ckw[c*4+t]; }
  const float bq = cqb[c], bk = ckb[c];
  const float qn = qnw[lane], kn = knw[lane];
  const int lr0 = l0 + wave*16;
  const long base = ((long)bh*L_ + lr0)*64 + lane;

  float hq[3], hk[3];
  #pragma unroll
  for (int t=0;t<3;++t){
    const bool ok = (lr0 + t - 3) >= 0;
    const long off = base + (long)(t-3)*64;
    hq[t] = ok ? bf2f(qg[off]) : 0.f;
    hk[t] = ok ? bf2f(kg[off]) : 0.f;
  }
  for (int r=0;r<16;++r){
    const long off = base + (long)r*64;
    const float cq = bf2f(qg[off]);
    const float ck = bf2f(kg[off]);
    float aq = bq + wq[0]*hq[0] + wq[1]*hq[1] + wq[2]*hq[2] + wq[3]*cq;
    float ak = bk + wk[0]*hk[0] + wk[1]*hk[1] + wk[2]*hk[2] + wk[3]*ck;
    hq[0]=hq[1]; hq[1]=hq[2]; hq[2]=cq;
    hk[0]=hk[1]; hk[1]=hk[2]; hk[2]=ck;
    const float yq = aq*sigf(aq), yk = ak*sigf(ak);
    const float ssq = wsum64(yq*yq);
    const float ssk = wsum64(yk*yk);
    sq[off] = (unsigned short)f2bfu(qn * yq * rsqrtf(ssq*(1.0f/64.0f) + EPS_));
    sk[off] = (unsigned short)f2bfu(kn * yk * rsqrtf(ssk*(1.0f/64.0f) + EPS_));
  }
}

// ---------------------------------------------------------------------------
// MFMA chunk scan, 512 threads (8 waves), 5 barriers/chunk.
// Phase A: P2(n)+P8(n-1) share W1T b-frags. Phase B: P4(n)+P9'(n-1) share
// W2T frags (y computed transposed -> coalesced fp32 stores), kmom/xmom
// partials row-sliced over all waves, staging writes. C: P5 + moment finals
// + w2mom partials. D: w1mom partials + w2mom final. E: rank-1 updates.
// ---------------------------------------------------------------------------
#define SK 68    // u16 stride, 64-wide arrays
#define SX 132   // u16 stride, 128-wide arrays

__global__ __launch_bounds__(512, 1) void scan_kernel(
  const unsigned short* __restrict__ sq, const unsigned short* __restrict__ sk,
  const unsigned short* __restrict__ vraw,
  const float* __restrict__ cmg, const float* __restrict__ c1g,
  const float* __restrict__ ppg,
  const float* __restrict__ cvw, const float* __restrict__ cvb,
  const float* __restrict__ W1in, const float* __restrict__ W2in,
  float* __restrict__ out)
{
  const int bh = blockIdx.x;
  const int h = bh & 15;
  const int tid = threadIdx.x;
  const int lane = tid & 63, wave = tid >> 6;
  const int lq = lane & 15, quad = lane >> 4;
  const int r2 = wave & 3, cw = wave >> 2;
  const int rw = r2 * 16;
  const int i0 = wave * 8;

  // u16 offsets: kcs[s]=s*4352; qcs[s]=8704+s*4352; gms[s]=17408+s*4352;
  // xbs=26112; hqs=34560; W1T=43008; W2n=51712; W2T=60416; end=68864
  __shared__ __align__(16) unsigned short sm[68864];
  unsigned short* xbs = sm + 26112;
  unsigned short* hqs = sm + 34560;
  unsigned short* W1T = sm + 43008;
  unsigned short* W2n = sm + 51712;
  unsigned short* W2T = sm + 60416;
  __shared__ float cmA[2][64], c1A[2][64], ppS[2][2];
  __shared__ float kmomS[64], xmomS[128], w2momS[64];
  __shared__ float pK[8][64], pX[8][128], pW1[8][128], pW2[8][64];

  // ---- init state ----
  {
    const int j = tid >> 2, q0 = (tid & 3) * 16;
    const float* w1p = W1in + (size_t)h * D_ * DM_;
    #pragma unroll 4
    for (int t=0;t<16;++t)
      W1T[j*SK + q0 + t] = (unsigned short)f2bfu(w1p[(size_t)(q0+t)*DM_ + j]);
    const float* w2p = W2in + (size_t)h * DM_ * D_ + (size_t)j*D_ + q0;
    #pragma unroll 4
    for (int t=0;t<16;++t){
      unsigned short v = (unsigned short)f2bfu(w2p[t]);
      W2n[j*SK + q0 + t] = v;
      W2T[(q0+t)*SX + j] = v;
    }
  }
  if (tid < 64){ kmomS[tid]=0.f; w2momS[tid]=0.f; }
  if (tid < 128){ xmomS[tid]=0.f; }
  float w1m_reg = 0.f;   // persistent w1mom[j] for j = tid>>2

  const int c = h*64 + lane;
  float wvc[4];
  #pragma unroll
  for (int t=0;t<4;++t) wvc[t] = cvw[c*4+t];
  const float bvc = cvb[c];
  const long sbase = (long)bh * L_ * 64;
  const long vbase = sbase + lane;

  uint4 kreg, qreg; float vr[11];
  float cmr=0.f, c1r=0.f, ppr=0.f;

  auto stage_load = [&](int m){
    if (m >= NCH_) return;
    kreg = *(const uint4*)&sk[sbase + (long)(m*64 + i0)*64 + lane*8];
    qreg = *(const uint4*)&sq[sbase + (long)(m*64 + i0)*64 + lane*8];
    #pragma unroll
    for (int t=0;t<11;++t){
      const int gl = m*64 + i0 + t - 3;
      vr[t] = (gl >= 0) ? bf2f(vraw[vbase + (long)gl*64]) : 0.f;
    }
    if (wave == 0){
      cmr = cmg[((size_t)bh*NCH_ + m)*64 + lane];
      c1r = c1g[((size_t)bh*NCH_ + m)*64 + lane];
    }
    if (tid < 2) ppr = ppg[((size_t)bh*NCH_ + m)*2 + tid];
  };

  auto stage_store = [&](int m){
    if (m >= NCH_) return;
    const int s = m & 1;
    unsigned short* kc = sm + s*4352;
    unsigned short* qc = sm + 8704 + s*4352;
    unsigned short* gm = sm + 17408 + s*4352;
    const int wr = i0 + (lane >> 3), wc = (lane & 7)*8;
    *(uint4*)&kc[wr*SK + wc] = kreg;
    *(uint4*)&qc[wr*SK + wc] = qreg;
    #pragma unroll
    for (int i=0;i<8;++i){
      const float av = bvc + wvc[0]*vr[i] + wvc[1]*vr[i+1] + wvc[2]*vr[i+2] + wvc[3]*vr[i+3];
      gm[(i0+i)*SK + lane] = (unsigned short)f2bfu(av*sigf(av));
    }
    if (wave == 0){ cmA[s][lane] = cmr; c1A[s][lane] = c1r; }
    if (tid < 2) ppS[s][tid] = ppr;
  };

  stage_load(0);
  stage_store(0);
  __syncthreads();

  for (int n = 0; n < NCH_; ++n){
    const int cur = n & 1;
    const unsigned short* kcs = sm + cur*4352;
    const unsigned short* qcsP = sm + 8704 + (cur^1)*4352;   // chunk n-1 slot
    unsigned short* gms = sm + 17408 + cur*4352;

    stage_load(n+1);

    // ================= Phase A: P2(n) + P8(n-1) =================
    facc_t zk[4];
    {
      bfrag_t w1b0[4], w1b1[4];
      #pragma unroll
      for (int nt=0;nt<4;++nt){
        const int j = cw*64 + nt*16 + lq;
        w1b0[nt] = *(const bfrag_t*)&W1T[j*SK + quad*8];
        w1b1[nt] = *(const bfrag_t*)&W1T[j*SK + 32 + quad*8];
      }
      const bfrag_t ak0 = *(const bfrag_t*)&kcs[(rw+lq)*SK + quad*8];
      const bfrag_t ak1 = *(const bfrag_t*)&kcs[(rw+lq)*SK + 32 + quad*8];
      const int rb = rw + quad*4;
      #pragma unroll
      for (int nt=0;nt<4;++nt){
        const int j = cw*64 + nt*16 + lq;
        facc_t z = {0.f,0.f,0.f,0.f};
        z = MFMA16(ak0, w1b0[nt], z);
        z = MFMA16(ak1, w1b1[nt], z);
        zk[nt] = z;
        #pragma unroll
        for (int r=0;r<4;++r)
          xbs[(rb+r)*SX + j] = (unsigned short)f2bfu(z[r]*sigf(z[r]));
      }
      if (n > 0){
        const bfrag_t aq0 = *(const bfrag_t*)&qcsP[(rw+lq)*SK + quad*8];
        const bfrag_t aq1 = *(const bfrag_t*)&qcsP[(rw+lq)*SK + 32 + quad*8];
        #pragma unroll
        for (int nt=0;nt<4;++nt){
          const int j = cw*64 + nt*16 + lq;
          facc_t hz = {0.f,0.f,0.f,0.f};
          hz = MFMA16(aq0, w1b0[nt], hz);
          hz = MFMA16(aq1, w1b1[nt], hz);
          #pragma unroll
          for (int r=0;r<4;++r)
            hqs[(rb+r)*SX + j] = (unsigned short)f2bfu(hz[r]*sigf(hz[r]));
        }
      }
    }
    __syncthreads();   // bA

    // ========= Phase B: staging + P4(n) + P9'(n-1) + km/xm partials =========
    stage_store(n+1);
    {
      bfrag_t w2b[2][4];
      #pragma unroll
      for (int nt=0;nt<2;++nt)
        #pragma unroll
        for (int kt=0;kt<4;++kt)
          w2b[nt][kt] = *(const bfrag_t*)&W2T[(cw*32+nt*16+lq)*SX + kt*32 + quad*8];
      bfrag_t xa[4];
      #pragma unroll
      for (int kt=0;kt<4;++kt)
        xa[kt] = *(const bfrag_t*)&xbs[(rw+lq)*SX + kt*32 + quad*8];
      const int rb = rw + quad*4;
      #pragma unroll
      for (int nt=0;nt<2;++nt){
        const int e = cw*32 + nt*16 + lq;
        facc_t g = {0.f,0.f,0.f,0.f};
        #pragma unroll
        for (int kt=0;kt<4;++kt) g = MFMA16(xa[kt], w2b[nt][kt], g);
        #pragma unroll
        for (int r=0;r<4;++r){
          const float gv = g[r] - bf2f(gms[(rb+r)*SK + e]);
          gms[(rb+r)*SK + e] = (unsigned short)f2bfu(gv);
        }
      }
      if (n > 0){
        const int ebsel = r2 & 1;
        const int e0 = cw*32 + ebsel*16 + quad*4;
        #pragma unroll
        for (int lb2=0; lb2<2; ++lb2){
          const int lb = (r2>>1)*2 + lb2;
          facc_t y = {0.f,0.f,0.f,0.f};
          #pragma unroll
          for (int kt=0;kt<4;++kt){
            const bfrag_t hb = *(const bfrag_t*)&hqs[(lb*16+lq)*SX + kt*32 + quad*8];
            y = MFMA16(w2b[ebsel][kt], hb, y);
          }
          #pragma unroll
          for (int r=0;r<4;++r)
            out[((size_t)bh*64 + e0 + r)*L_ + (n-1)*64 + lb*16 + lq] = y[r];
        }
      }
      // kmom/xmom partials (rows i0..i0+7)
      float accK = 0.f, accX0 = 0.f, accX1 = 0.f;
      #pragma unroll
      for (int t=0;t<8;++t){
        const float cmt = cmA[cur][i0+t];
        accK += cmt * bf2f(kcs[(i0+t)*SK + lane]);
        const unsigned px = *(const unsigned*)&xbs[(i0+t)*SX + 2*lane];
        accX0 += cmt * bf2f((unsigned short)(px & 0xffffu));
        accX1 += cmt * bf2f((unsigned short)(px >> 16));
      }
      pK[wave][lane] = accK;
      pX[wave][2*lane] = accX0;
      pX[wave][2*lane+1] = accX1;
    }
    __syncthreads();   // bB

    // ====== Phase C: P5 + kmom/xmom finals + w2mom partials ======
    {
      const bfrag_t ag0 = *(const bfrag_t*)&gms[(rw+lq)*SK + quad*8];
      const bfrag_t ag1 = *(const bfrag_t*)&gms[(rw+lq)*SK + 32 + quad*8];
      const int rb = rw + quad*4;
      #pragma unroll
      for (int nt=0;nt<4;++nt){
        const int j = cw*64 + nt*16 + lq;
        const bfrag_t b0 = *(const bfrag_t*)&W2n[j*SK + quad*8];
        const bfrag_t b1 = *(const bfrag_t*)&W2n[j*SK + 32 + quad*8];
        facc_t gz = {0.f,0.f,0.f,0.f};
        gz = MFMA16(ag0, b0, gz);
        gz = MFMA16(ag1, b1, gz);
        #pragma unroll
        for (int r=0;r<4;++r){
          const float zz = zk[nt][r];
          const float sg = sigf(zz);
          xbs[(rb+r)*SX + j] = (unsigned short)f2bfu(gz[r] * (sg*(1.0f + zz*(1.0f-sg))));
        }
      }
      if (tid < 64){
        float a = 0.f;
        #pragma unroll
        for (int w=0;w<8;++w) a += pK[w][tid];
        kmomS[tid] = ppS[cur][0]*kmomS[tid] + a;
      } else if (tid < 192){
        const int j = tid - 64;
        float a = 0.f;
        #pragma unroll
        for (int w=0;w<8;++w) a += pX[w][j];
        xmomS[j] = ppS[cur][0]*xmomS[j] + a;
      }
      float accW2 = 0.f;
      #pragma unroll
      for (int t=0;t<8;++t)
        accW2 += c1A[cur][i0+t] * bf2f(gms[(i0+t)*SK + lane]);
      pW2[wave][lane] = accW2;
    }
    __syncthreads();   // bC

    // ====== Phase D: w1mom partials + w2mom final ======
    {
      float a0 = 0.f, a1 = 0.f;
      #pragma unroll
      for (int t=0;t<8;++t){
        const float c1t = c1A[cur][i0+t];
        const unsigned px = *(const unsigned*)&xbs[(i0+t)*SX + 2*lane];
        a0 += c1t * bf2f((unsigned short)(px & 0xffffu));
        a1 += c1t * bf2f((unsigned short)(px >> 16));
      }
      pW1[wave][2*lane] = a0;
      pW1[wave][2*lane+1] = a1;
      if (tid >= 192 && tid < 256){
        const int e = tid - 192;
        float a = 0.f;
        #pragma unroll
        for (int w=0;w<8;++w) a += pW2[w][e];
        w2momS[e] = ppS[cur][1]*w2momS[e] + a;
      }
    }
    __syncthreads();   // bD

    // ====== Phase E: rank-1 state updates ======
    {
      const float Pmd = ppS[cur][0], Psd = ppS[cur][1];
      const int j = tid >> 2, q0 = (tid & 3)*16;
      // w1mom[j] (persistent register)
      {
        float a = 0.f;
        #pragma unroll
        for (int w=0;w<8;++w) a += pW1[w][j];
        w1m_reg = Psd*w1m_reg + a;
      }
      float km[16], wm2[16];
      *(float4*)&km[0]  = *(const float4*)&kmomS[q0];
      *(float4*)&km[4]  = *(const float4*)&kmomS[q0+4];
      *(float4*)&km[8]  = *(const float4*)&kmomS[q0+8];
      *(float4*)&km[12] = *(const float4*)&kmomS[q0+12];
      *(float4*)&wm2[0]  = *(const float4*)&w2momS[q0];
      *(float4*)&wm2[4]  = *(const float4*)&w2momS[q0+4];
      *(float4*)&wm2[8]  = *(const float4*)&w2momS[q0+8];
      *(float4*)&wm2[12] = *(const float4*)&w2momS[q0+12];
      const float xm = xmomS[j];
      #pragma unroll
      for (int half=0; half<16; half+=8){
        const int off = j*SK + q0 + half;
        bfrag_t wv = *(const bfrag_t*)&W1T[off];
        alignas(16) unsigned short o[8];
        #pragma unroll
        for (int s2=0;s2<8;++s2)
          o[s2] = (unsigned short)f2bfu(Pmd*bf2f((unsigned short)wv[s2]) + w1m_reg*km[half+s2]);
        *(bfrag_t*)&W1T[off] = *(const bfrag_t*)o;
      }
      #pragma unroll
      for (int half=0; half<16; half+=8){
        const int off = j*SK + q0 + half;
        bfrag_t wv = *(const bfrag_t*)&W2n[off];
        alignas(16) unsigned short o[8];
        #pragma unroll
        for (int s2=0;s2<8;++s2)
          o[s2] = (unsigned short)f2bfu(Pmd*bf2f((unsigned short)wv[s2]) + xm*wm2[half+s2]);
        *(bfrag_t*)&W2n[off] = *(const bfrag_t*)o;
      }
      const int e2 = tid >> 3, js = (tid & 7)*16;
      float xv[16];
      *(float4*)&xv[0]  = *(const float4*)&xmomS[js];
      *(float4*)&xv[4]  = *(const float4*)&xmomS[js+4];
      *(float4*)&xv[8]  = *(const float4*)&xmomS[js+8];
      *(float4*)&xv[12] = *(const float4*)&xmomS[js+12];
      const float w2m = w2momS[e2];
      #pragma unroll
      for (int half=0; half<16; half+=8){
        const int off = e2*SX + js + half;
        bfrag_t wv = *(const bfrag_t*)&W2T[off];
        alignas(16) unsigned short o[8];
        #pragma unroll
        for (int s2=0;s2<8;++s2)
          o[s2] = (unsigned short)f2bfu(Pmd*bf2f((unsigned short)wv[s2]) + xv[half+s2]*w2m);
        *(bfrag_t*)&W2T[off] = *(const bfrag_t*)o;
      }
    }
    __syncthreads();   // bE
  }

  // ================= Epilogue: P8(63) then P9'(63) =================
  {
    const unsigned short* qcsL = sm + 8704 + 4352;   // slot 1 = chunk 63
    const bfrag_t aq0 = *(const bfrag_t*)&qcsL[(rw+lq)*SK + quad*8];
    const bfrag_t aq1 = *(const bfrag_t*)&qcsL[(rw+lq)*SK + 32 + quad*8];
    const int rb = rw + quad*4;
    #pragma unroll
    for (int nt=0;nt<4;++nt){
      const int j = cw*64 + nt*16 + lq;
      const bfrag_t b0 = *(const bfrag_t*)&W1T[j*SK + quad*8];
      const bfrag_t b1 = *(const bfrag_t*)&W1T[j*SK + 32 + quad*8];
      facc_t hz = {0.f,0.f,0.f,0.f};
      hz = MFMA16(aq0, b0, hz);
      hz = MFMA16(aq1, b1, hz);
      #pragma unroll
      for (int r=0;r<4;++r)
        hqs[(rb+r)*SX + j] = (unsigned short)f2bfu(hz[r]*sigf(hz[r]));
    }
  }
  __syncthreads();
  {
    const int ebsel = r2 & 1;
    const int e0 = cw*32 + ebsel*16 + quad*4;
    bfrag_t w2a[4];
    #pragma unroll
    for (int kt=0;kt<4;++kt)
      w2a[kt] = *(const bfrag_t*)&W2T[(cw*32+ebsel*16+lq)*SX + kt*32 + quad*8];
    #pragma unroll
    for (int lb2=0; lb2<2; ++lb2){
      const int lb = (r2>>1)*2 + lb2;
      facc_t y = {0.f,0.f,0.f,0.f};
      #pragma unroll
      for (int kt=0;kt<4;++kt){
        const bfrag_t hb = *(const bfrag_t*)&hqs[(lb*16+lq)*SX + kt*32 + quad*8];
        y = MFMA16(w2a[kt], hb, y);
      }
      #pragma unroll
      for (int r=0;r<4;++r)
        out[((size_t)bh*64 + e0 + r)*L_ + 63*64 + lb*16 + lq] = y[r];
    }
  }
}

extern "C" void kernel_launch(void* const* d_in, const int* in_sizes, int n_in,
                              void* d_out, int out_size, void* d_ws, size_t ws_size,
                              hipStream_t stream)
{
  const float* x   = (const float*)d_in[0];
  const float* Wq  = (const float*)d_in[1];
  const float* Wk  = (const float*)d_in[2];
  const float* Wv  = (const float*)d_in[3];
  const float* cqw = (const float*)d_in[4];
  const float* cqb = (const float*)d_in[5];
  const float* ckw = (const float*)d_in[6];
  const float* ckb = (const float*)d_in[7];
  const float* cvw = (const float*)d_in[8];
  const float* cvb = (const float*)d_in[9];
  const float* qnw = (const float*)d_in[10];
  const float* knw = (const float*)d_in[11];
  const float* mdw = (const float*)d_in[12];
  const float* mdb = (const float*)d_in[13];
  const float* sw  = (const float*)d_in[14];
  const float* sb  = (const float*)d_in[15];
  const float* lw  = (const float*)d_in[16];
  const float* lb  = (const float*)d_in[17];
  const float* W1  = (const float*)d_in[18];
  const float* W2  = (const float*)d_in[19];
  float* out = (float*)d_out;

  const size_t SZ  = (size_t)B_ * L_ * HID_;   // 16,777,216
  const size_t WSZ = (size_t)HID_ * HID_;
  unsigned short* xb  = (unsigned short*)d_ws;   // x bf16; reused as sq after GEMM
  unsigned short* wqb = xb  + SZ;
  unsigned short* wkb = wqb + WSZ;
  unsigned short* wvb = wkb + WSZ;
  unsigned short* qb  = wvb + WSZ;   // raw q/k/v head-major bf16
  unsigned short* kb  = qb  + SZ;
  unsigned short* vb  = kb  + SZ;
  unsigned short* skb = vb  + SZ;    // staged k
  float* cmb = (float*)(skb + SZ);
  float* c1b = cmb + (size_t)B_*H_*NCH_*64;
  float* ppb = c1b + (size_t)B_*H_*NCH_*64;

  cast_kernel<<<16384 + 3*1024, 256, 0, stream>>>(x, Wq, Wk, Wv, xb, wqb, wkb, wvb);
  dim3 gg(3*HID_/128, (B_*L_)/128);
  gemm_bf16_nt<<<gg, 256, 0, stream>>>(xb, wqb, qb, B_*L_, 3*HID_, HID_);
  gates_kernel<<<(B_*L_)/64, 256, 0, stream>>>(x, mdw, mdb, sw, sb, lw, lb, cmb, c1b, ppb);
  // stage q/k (xb is dead as GEMM input now; reuse as staged q)
  stage_kernel<<<B_*H_*64, 256, 0, stream>>>(qb, kb, xb, skb,
                                             cqw, cqb, ckw, ckb, qnw, knw);
  scan_kernel<<<B_*H_, 512, 0, stream>>>(xb, skb, vb, cmb, c1b, ppb,
                                         cvw, cvb, W1, W2, out);
}